// Round 11
// baseline (209.622 us; speedup 1.0000x reference)
//
#include <hip/hip_runtime.h>
#include <stdint.h>

#define N_PP   8192
#define DIM    16
#define NEDGE  262144
#define LOG2E  1.4426950408889634f
#define CH     16      // tiles per staged chunk

// ---- ws float-unit layout (~1.12 MB) ----
// [0]=nonlink_pp [1]=link_pp [2]=nonlink_ap [3]=link_ap [4]=counter(uint)
// p_star rows are 48 B (12 u32): [-2x packed x8][pack(x2,1)][0][0][0]
// so MFMA(A,B) with B=[y(16),1,y2] yields d2 = x2+y2-2<x,y> directly.
#define WS_PSBF 512
#define WS_PBF  (WS_PSBF + 98304)   // p rows, 32 B
#define WS_ABF  (WS_PBF  + 65536)   // a rows, 32 B
#define WS_Y2P  (WS_ABF  + 65536)
#define WS_Y2A  (WS_Y2P  + 8192)
#define WS_EGC  (WS_Y2A  + 8192)    // exp(gamma_pp[8192+j])
#define WS_EBC  (WS_EGC  + 8192)    // exp(beta_ap[8192+j])
#define WS_GL2  (WS_EBC  + 8192)    // gamma_pp[i]*LOG2E
#define WS_BL2  (WS_GL2  + 8192)    // beta_ap[i]*LOG2E

// Main grid: quantum = (128-col group g, 16-tile chunk c); wave = 2 strips.
// ap: 64 groups x 32 chunks = 2048.
// pp: group g needs floor(g/2)+1 chunks; band m = groups {2m,2m+1} with
// (m+1) chunks each, prefix m(m+1) -> total sum_{m=0}^{31} 2(m+1) = 1056.
// (R10 bug: this was 4160 -> ~3000 garbage blocks decoded g>=64.)
#define NQ_AP   2048
#define NQ_PP   1056
#define NB_MAT  (NQ_AP + NQ_PP)
#define NB_EDGE 256
#define NB_TOTAL (NB_MAT + NB_EDGE)

typedef short    bf16x8 __attribute__((ext_vector_type(8)));
typedef float    f32x4  __attribute__((ext_vector_type(4)));
typedef unsigned u32x4  __attribute__((ext_vector_type(4)));

__device__ __forceinline__ float waveReduce(float v) {
#pragma unroll
    for (int off = 32; off > 0; off >>= 1)
        v += __shfl_down(v, off, 64);
    return v;
}

__device__ __forceinline__ unsigned bf16_rne(float f) {
    unsigned u = __builtin_bit_cast(unsigned, f);
    return (u + 0x7FFFu + ((u >> 16) & 1u)) >> 16;
}
__device__ __forceinline__ unsigned packbf2(float a, float b) {
    return bf16_rne(a) | (bf16_rne(b) << 16);
}

// Async global->LDS DMA, 16 B/lane, lane i lands at ldsbase + i*16.
__device__ __forceinline__ void gload_lds(const uint32_t* g, uint32_t* l) {
    __builtin_amdgcn_global_load_lds(
        (const __attribute__((address_space(1))) void*)(uintptr_t)g,
        (__attribute__((address_space(3))) void*)(unsigned)(uintptr_t)l,
        16, 0, 0);
}

// 224 blocks x 256: conversions + bias arrays + accumulator zeroing.
__global__ __launch_bounds__(256) void pre_kernel(
    const float* __restrict__ p_star, const float* __restrict__ p,
    const float* __restrict__ a, const float* __restrict__ beta_ap,
    const float* __restrict__ gamma_pp, float* __restrict__ ws)
{
    const int g = blockIdx.x * 256 + threadIdx.x;
    if (g < 8) ws[g] = 0.0f;

    if (g < 8192) {                       // p_star -> 48 B MFMA-d2 rows
        const float4* rp = (const float4*)(p_star + g * DIM);
        float4 f0 = rp[0], f1 = rp[1], f2 = rp[2], f3 = rp[3];
        float x2 = f0.x*f0.x + f0.y*f0.y + f0.z*f0.z + f0.w*f0.w
                 + f1.x*f1.x + f1.y*f1.y + f1.z*f1.z + f1.w*f1.w
                 + f2.x*f2.x + f2.y*f2.y + f2.z*f2.z + f2.w*f2.w
                 + f3.x*f3.x + f3.y*f3.y + f3.z*f3.z + f3.w*f3.w;
        u32x4 u0 = { packbf2(-2.f*f0.x, -2.f*f0.y), packbf2(-2.f*f0.z, -2.f*f0.w),
                     packbf2(-2.f*f1.x, -2.f*f1.y), packbf2(-2.f*f1.z, -2.f*f1.w) };
        u32x4 u1 = { packbf2(-2.f*f2.x, -2.f*f2.y), packbf2(-2.f*f2.z, -2.f*f2.w),
                     packbf2(-2.f*f3.x, -2.f*f3.y), packbf2(-2.f*f3.z, -2.f*f3.w) };
        u32x4 u2 = { packbf2(x2, 1.0f), 0u, 0u, 0u };
        uint32_t* dst = (uint32_t*)(ws + WS_PSBF) + g * 12;
        *(u32x4*)dst = u0; *(u32x4*)(dst + 4) = u1; *(u32x4*)(dst + 8) = u2;
    } else if (g < 3 * 8192) {            // p / a -> 32 B rows + |y|^2
        const int arr = (g >> 13) - 1, idx = g & 8191;
        const float* src = arr == 0 ? p : a;
        const int bfo = arr == 0 ? WS_PBF : WS_ABF;
        const int n2o = arr == 0 ? WS_Y2P : WS_Y2A;
        const float4* rp = (const float4*)(src + idx * DIM);
        float4 f0 = rp[0], f1 = rp[1], f2 = rp[2], f3 = rp[3];
        float n2 = f0.x*f0.x + f0.y*f0.y + f0.z*f0.z + f0.w*f0.w
                 + f1.x*f1.x + f1.y*f1.y + f1.z*f1.z + f1.w*f1.w
                 + f2.x*f2.x + f2.y*f2.y + f2.z*f2.z + f2.w*f2.w
                 + f3.x*f3.x + f3.y*f3.y + f3.z*f3.z + f3.w*f3.w;
        u32x4 u0 = { packbf2(f0.x, f0.y), packbf2(f0.z, f0.w),
                     packbf2(f1.x, f1.y), packbf2(f1.z, f1.w) };
        u32x4 u1 = { packbf2(f2.x, f2.y), packbf2(f2.z, f2.w),
                     packbf2(f3.x, f3.y), packbf2(f3.z, f3.w) };
        u32x4* dst = (u32x4*)(ws + bfo) + idx * 2;
        dst[0] = u0; dst[1] = u1;
        ws[n2o + idx] = n2;
    } else if (g < 7 * 8192) {            // bias arrays
        const int h = g - 3 * 8192, q = h >> 13, i = h & 8191;
        if      (q == 0) ws[WS_EGC + i] = __expf(gamma_pp[8192 + i]);
        else if (q == 1) ws[WS_EBC + i] = __expf(beta_ap[8192 + i]);
        else if (q == 2) ws[WS_GL2 + i] = gamma_pp[i] * LOG2E;
        else             ws[WS_BL2 + i] = beta_ap[i] * LOG2E;
    }
}

__global__ void main_kernel(
    const float* __restrict__ p_star, const float* __restrict__ p,
    const float* __restrict__ a, const float* __restrict__ beta_ap,
    const float* __restrict__ gamma_pp, const int* __restrict__ edges_pp,
    const int* __restrict__ edges_ap, float* __restrict__ ws,
    float* __restrict__ out)
{
    // sbuf: [0,3072) 16 tiles x 16 rows x 12 u32; [3072,3328) bias floats
    __shared__ uint32_t sbuf[3328];
    __shared__ float smred[4];
    const int b = blockIdx.x, tid = threadIdx.x, wid = tid >> 6;
    const int lane = tid & 63, quad = lane >> 4, l16 = lane & 15;

    float val = 0.f;
    int slot;

    if (b < NB_MAT) {
        const bool isPP = (b >= NQ_AP);
        int g, c;
        if (!isPP) { g = b >> 5; c = b & 31; }
        else {
            const int qq = b - NQ_AP;
            int m = 0;
            while ((m + 1) * (m + 2) <= qq) ++m;     // band index (uniform SALU)
            const int r = qq - m * (m + 1);
            const int dv = r / (m + 1);
            g = 2 * m + dv; c = r - dv * (m + 1);
        }
        const int t0 = c << 4;
        slot = isPP ? 0 : 2;

        const uint32_t* Xbf = (const uint32_t*)(ws + WS_PSBF);
        const uint32_t* Ybf = (const uint32_t*)(ws + (isPP ? WS_PBF : WS_ABF));
        const float* y2  = ws + (isPP ? WS_Y2P : WS_Y2A);
        const float* gl2 = ws + (isPP ? WS_GL2 : WS_BL2);
        const float* EcA = ws + (isPP ? WS_EGC : WS_EBC);

        // ---- per-wave: two adjacent 16-col strips ----
        const int sA = (g << 3) + (wid << 1);
        bf16x8 bfrag[2];
        float  Ec[2];
#pragma unroll
        for (int ss = 0; ss < 2; ++ss) {
            const int j = ((sA + ss) << 4) + l16;
            u32x4 bu = {0u, 0u, 0u, 0u};
            if (quad < 2)       bu = *(const u32x4*)(Ybf + j * 8 + (quad << 2));
            else if (quad == 2) bu.x = packbf2(1.0f, y2[j]);   // k16=1, k17=y2
            bfrag[ss] = __builtin_bit_cast(bf16x8, bu);
            Ec[ss] = EcA[j];
        }

        // ---- stage chunk: 12 KB A-rows + 1 KB bias, async DMA ----
        for (int k = wid; k < 13; k += 4) {
            const uint32_t* gsrc;
            int loff;
            if (k < 12) { gsrc = Xbf + t0 * 192 + (k << 8); loff = k << 8; }
            else        { gsrc = (const uint32_t*)(gl2 + (t0 << 4)); loff = 3072; }
            gload_lds(gsrc + (lane << 2), &sbuf[loff]);
        }
        __syncthreads();   // drains DMA, staging visible

        const f32x4 zero4 = {0.f, 0.f, 0.f, 0.f};
        const int aq4 = (quad < 2 ? quad : 2) << 2;   // quad3 aliases quad2 (x B=0)
        float acc0 = 0.f, acc1 = 0.f;

        auto full_tile = [&](int t) {
            const int tl = t - t0;
            const u32x4 au = *(const u32x4*)&sbuf[tl * 192 + l16 * 12 + aq4];
            const f32x4 ag4 = *(const f32x4*)((const float*)sbuf + 3072 + (tl << 4) + (quad << 2));
            f32x4 d0 = __builtin_amdgcn_mfma_f32_16x16x32_bf16(
                __builtin_bit_cast(bf16x8, au), bfrag[0], zero4, 0, 0, 0);
            f32x4 d1 = __builtin_amdgcn_mfma_f32_16x16x32_bf16(
                __builtin_bit_cast(bf16x8, au), bfrag[1], zero4, 0, 0, 0);
#pragma unroll
            for (int r = 0; r < 4; ++r) {
                float q0 = fmaxf(d0[r], 0.f), q1 = fmaxf(d1[r], 0.f);
                acc0 += __builtin_amdgcn_exp2f(
                    fmaf(-LOG2E, __builtin_amdgcn_sqrtf(q0), ag4[r]));
                acc1 += __builtin_amdgcn_exp2f(
                    fmaf(-LOG2E, __builtin_amdgcn_sqrtf(q1), ag4[r]));
            }
        };

        const int tFull = isPP ? (sA < t0 + CH ? sA : t0 + CH) : t0 + CH;
        int t = t0;
        for (; t + 1 < tFull; t += 2) { full_tile(t); full_tile(t + 1); }
        if (t < tFull) full_tile(t);

        if (isPP && sA < t0 + CH) {       // diagonal pair (last chunk only: sA>=t0)
            {   // tile t=sA: ss0 diagonal-masked, ss1 full
                const int tl = sA - t0;
                const u32x4 au = *(const u32x4*)&sbuf[tl * 192 + l16 * 12 + aq4];
                const f32x4 ag4 = *(const f32x4*)((const float*)sbuf + 3072 + (tl << 4) + (quad << 2));
                f32x4 d0 = __builtin_amdgcn_mfma_f32_16x16x32_bf16(
                    __builtin_bit_cast(bf16x8, au), bfrag[0], zero4, 0, 0, 0);
                f32x4 d1 = __builtin_amdgcn_mfma_f32_16x16x32_bf16(
                    __builtin_bit_cast(bf16x8, au), bfrag[1], zero4, 0, 0, 0);
#pragma unroll
                for (int r = 0; r < 4; ++r) {
                    float q0 = fmaxf(d0[r], 0.f), q1 = fmaxf(d1[r], 0.f);
                    float t0v = __builtin_amdgcn_exp2f(
                        fmaf(-LOG2E, __builtin_amdgcn_sqrtf(q0), ag4[r]));
                    if (l16 <= (quad << 2) + r) t0v = 0.f;   // strict j > i
                    acc0 += t0v;
                    acc1 += __builtin_amdgcn_exp2f(
                        fmaf(-LOG2E, __builtin_amdgcn_sqrtf(q1), ag4[r]));
                }
            }
            {   // tile t=sA+1: ss1 diagonal-masked only
                const int tl = sA + 1 - t0;
                const u32x4 au = *(const u32x4*)&sbuf[tl * 192 + l16 * 12 + aq4];
                const f32x4 ag4 = *(const f32x4*)((const float*)sbuf + 3072 + (tl << 4) + (quad << 2));
                f32x4 d1 = __builtin_amdgcn_mfma_f32_16x16x32_bf16(
                    __builtin_bit_cast(bf16x8, au), bfrag[1], zero4, 0, 0, 0);
#pragma unroll
                for (int r = 0; r < 4; ++r) {
                    float q1 = fmaxf(d1[r], 0.f);
                    float t1v = __builtin_amdgcn_exp2f(
                        fmaf(-LOG2E, __builtin_amdgcn_sqrtf(q1), ag4[r]));
                    if (l16 <= (quad << 2) + r) t1v = 0.f;
                    acc1 += t1v;
                }
            }
        }
        val = acc0 * Ec[0] + acc1 * Ec[1];
    } else {
        // ---- edge tail blocks: 128 pp + 128 ap, 2048 edges each ----
        const int  eb   = b - NB_MAT;
        const bool isPP = (eb < 128);
        const int  base = (isPP ? eb : eb - 128) * 2048;
        slot = isPP ? 1 : 3;
        float sum = 0.f;
#pragma unroll
        for (int k = 0; k < 8; ++k) {
            const int e = base + k * 256 + tid;
            const float* yrow;
            float bias;
            int e0;
            if (isPP) {
                e0 = edges_pp[e];
                int e1 = edges_pp[NEDGE + e];
                yrow = p + e1 * DIM;
                bias = gamma_pp[e0] + gamma_pp[N_PP + e1];
            } else {
                e0 = edges_ap[e];
                int e1 = edges_ap[NEDGE + e];
                yrow = a + (e1 - N_PP) * DIM;
                bias = beta_ap[e0] + beta_ap[e1];
            }
            const float4* xp = (const float4*)(p_star + e0 * DIM);
            const float4* yp = (const float4*)yrow;
            float d2 = 0.f;
#pragma unroll
            for (int kk = 0; kk < 4; ++kk) {
                float4 xv = xp[kk], yv = yp[kk];
                float dx = xv.x - yv.x, dy = xv.y - yv.y,
                      dz = xv.z - yv.z, dw = xv.w - yv.w;
                d2 += dx*dx + dy*dy + dz*dz + dw*dw;
            }
            sum += bias - __builtin_amdgcn_sqrtf(d2);
        }
        val = sum;
    }

    float wsum = waveReduce(val);
    if ((tid & 63) == 0) smred[wid] = wsum;
    __syncthreads();
    if (tid == 0) {
        atomicAdd(&ws[slot], smred[0] + smred[1] + smred[2] + smred[3]);
        __threadfence();
        unsigned old = atomicAdd((unsigned*)(ws + 4), 1u);
        if (old == NB_TOTAL - 1) {
            float s0 = atomicAdd(&ws[0], 0.f), s1 = atomicAdd(&ws[1], 0.f);
            float s2 = atomicAdd(&ws[2], 0.f), s3 = atomicAdd(&ws[3], 0.f);
            out[0] = 0.5f * (s0 - s1) / (float)N_PP
                   + 0.5f * (s2 - s3) / (float)N_PP;
        }
    }
}

extern "C" void kernel_launch(void* const* d_in, const int* in_sizes, int n_in,
                              void* d_out, int out_size, void* d_ws, size_t ws_size,
                              hipStream_t stream) {
    const float* p_star   = (const float*)d_in[0];
    const float* p        = (const float*)d_in[1];
    const float* a        = (const float*)d_in[2];
    const float* beta_ap  = (const float*)d_in[3];
    const float* gamma_pp = (const float*)d_in[4];
    const int*   edges_pp = (const int*)d_in[5];
    const int*   edges_ap = (const int*)d_in[6];

    float* ws  = (float*)d_ws;
    float* out = (float*)d_out;

    hipLaunchKernelGGL(pre_kernel, dim3(224), dim3(256), 0, stream,
                       p_star, p, a, beta_ap, gamma_pp, ws);
    hipLaunchKernelGGL(main_kernel, dim3(NB_TOTAL), dim3(256), 0, stream,
                       p_star, p, a, beta_ap, gamma_pp, edges_pp, edges_ap, ws, out);
}

// Round 12
// 198.040 us; speedup vs baseline: 1.0585x; 1.0585x over previous
//
#include <hip/hip_runtime.h>
#include <stdint.h>

#define N_PP   8192
#define DIM    16
#define NEDGE  262144
#define LOG2E  1.4426950408889634f
#define CH     16      // tiles per staged chunk

// ---- ws float-unit layout (~1.12 MB) ----
// [0]=nonlink_pp [1]=link_pp [2]=nonlink_ap [3]=link_ap [4]=counter(uint)
// p_star rows are 48 B (12 u32): [-2x packed x8][pack(x2,1)][0][0][0]
// so MFMA(A,B) with B=[y(16),1,y2] yields d2 = x2+y2-2<x,y> directly.
#define WS_PSBF 512
#define WS_PBF  (WS_PSBF + 98304)   // p rows, 32 B
#define WS_ABF  (WS_PBF  + 65536)   // a rows, 32 B
#define WS_Y2P  (WS_ABF  + 65536)
#define WS_Y2A  (WS_Y2P  + 8192)
#define WS_EGC  (WS_Y2A  + 8192)    // exp(gamma_pp[8192+j])
#define WS_EBC  (WS_EGC  + 8192)    // exp(beta_ap[8192+j])
#define WS_GL2  (WS_EBC  + 8192)    // gamma_pp[i]*LOG2E
#define WS_BL2  (WS_GL2  + 8192)    // beta_ap[i]*LOG2E

// Main grid: quantum = (128-col group g, 16-tile chunk c); wave = 2 strips.
// ap: 64 groups x 32 chunks = 2048.
// pp: group g needs floor(g/2)+1 chunks; band m = groups {2m,2m+1} with
// (m+1) chunks each, prefix m(m+1) -> total 1056.
#define NQ_AP   2048
#define NQ_PP   1056
#define NB_MAT  (NQ_AP + NQ_PP)
#define NB_EDGE 256
#define NB_TOTAL (NB_MAT + NB_EDGE)

typedef short    bf16x8 __attribute__((ext_vector_type(8)));
typedef float    f32x4  __attribute__((ext_vector_type(4)));
typedef unsigned u32x4  __attribute__((ext_vector_type(4)));

__device__ __forceinline__ float waveReduce(float v) {
#pragma unroll
    for (int off = 32; off > 0; off >>= 1)
        v += __shfl_down(v, off, 64);
    return v;
}

__device__ __forceinline__ unsigned bf16_rne(float f) {
    unsigned u = __builtin_bit_cast(unsigned, f);
    return (u + 0x7FFFu + ((u >> 16) & 1u)) >> 16;
}
__device__ __forceinline__ unsigned packbf2(float a, float b) {
    return bf16_rne(a) | (bf16_rne(b) << 16);
}

// Async global->LDS DMA, 16 B/lane, lane i lands at ldsbase + i*16.
__device__ __forceinline__ void gload_lds(const uint32_t* g, uint32_t* l) {
    __builtin_amdgcn_global_load_lds(
        (const __attribute__((address_space(1))) void*)(uintptr_t)g,
        (__attribute__((address_space(3))) void*)(unsigned)(uintptr_t)l,
        16, 0, 0);
}

// 224 blocks x 256: conversions + bias arrays + accumulator zeroing.
__global__ __launch_bounds__(256) void pre_kernel(
    const float* __restrict__ p_star, const float* __restrict__ p,
    const float* __restrict__ a, const float* __restrict__ beta_ap,
    const float* __restrict__ gamma_pp, float* __restrict__ ws)
{
    const int g = blockIdx.x * 256 + threadIdx.x;
    if (g < 8) ws[g] = 0.0f;

    if (g < 8192) {                       // p_star -> 48 B MFMA-d2 rows
        const float4* rp = (const float4*)(p_star + g * DIM);
        float4 f0 = rp[0], f1 = rp[1], f2 = rp[2], f3 = rp[3];
        float x2 = f0.x*f0.x + f0.y*f0.y + f0.z*f0.z + f0.w*f0.w
                 + f1.x*f1.x + f1.y*f1.y + f1.z*f1.z + f1.w*f1.w
                 + f2.x*f2.x + f2.y*f2.y + f2.z*f2.z + f2.w*f2.w
                 + f3.x*f3.x + f3.y*f3.y + f3.z*f3.z + f3.w*f3.w;
        u32x4 u0 = { packbf2(-2.f*f0.x, -2.f*f0.y), packbf2(-2.f*f0.z, -2.f*f0.w),
                     packbf2(-2.f*f1.x, -2.f*f1.y), packbf2(-2.f*f1.z, -2.f*f1.w) };
        u32x4 u1 = { packbf2(-2.f*f2.x, -2.f*f2.y), packbf2(-2.f*f2.z, -2.f*f2.w),
                     packbf2(-2.f*f3.x, -2.f*f3.y), packbf2(-2.f*f3.z, -2.f*f3.w) };
        u32x4 u2 = { packbf2(x2, 1.0f), 0u, 0u, 0u };
        uint32_t* dst = (uint32_t*)(ws + WS_PSBF) + g * 12;
        *(u32x4*)dst = u0; *(u32x4*)(dst + 4) = u1; *(u32x4*)(dst + 8) = u2;
    } else if (g < 3 * 8192) {            // p / a -> 32 B rows + |y|^2
        const int arr = (g >> 13) - 1, idx = g & 8191;
        const float* src = arr == 0 ? p : a;
        const int bfo = arr == 0 ? WS_PBF : WS_ABF;
        const int n2o = arr == 0 ? WS_Y2P : WS_Y2A;
        const float4* rp = (const float4*)(src + idx * DIM);
        float4 f0 = rp[0], f1 = rp[1], f2 = rp[2], f3 = rp[3];
        float n2 = f0.x*f0.x + f0.y*f0.y + f0.z*f0.z + f0.w*f0.w
                 + f1.x*f1.x + f1.y*f1.y + f1.z*f1.z + f1.w*f1.w
                 + f2.x*f2.x + f2.y*f2.y + f2.z*f2.z + f2.w*f2.w
                 + f3.x*f3.x + f3.y*f3.y + f3.z*f3.z + f3.w*f3.w;
        u32x4 u0 = { packbf2(f0.x, f0.y), packbf2(f0.z, f0.w),
                     packbf2(f1.x, f1.y), packbf2(f1.z, f1.w) };
        u32x4 u1 = { packbf2(f2.x, f2.y), packbf2(f2.z, f2.w),
                     packbf2(f3.x, f3.y), packbf2(f3.z, f3.w) };
        u32x4* dst = (u32x4*)(ws + bfo) + idx * 2;
        dst[0] = u0; dst[1] = u1;
        ws[n2o + idx] = n2;
    } else if (g < 7 * 8192) {            // bias arrays
        const int h = g - 3 * 8192, q = h >> 13, i = h & 8191;
        if      (q == 0) ws[WS_EGC + i] = __expf(gamma_pp[8192 + i]);
        else if (q == 1) ws[WS_EBC + i] = __expf(beta_ap[8192 + i]);
        else if (q == 2) ws[WS_GL2 + i] = gamma_pp[i] * LOG2E;
        else             ws[WS_BL2 + i] = beta_ap[i] * LOG2E;
    }
}

// (256,3): budget ~170 VGPRs -> no spill (R11 spilled at the compiler's
// default 64-VGPR target: WRITE_SIZE 0.1->29.9 MB). 3 blocks/CU by waves;
// LDS would allow 11.
__global__ __launch_bounds__(256, 3) void main_kernel(
    const float* __restrict__ p_star, const float* __restrict__ p,
    const float* __restrict__ a, const float* __restrict__ beta_ap,
    const float* __restrict__ gamma_pp, const int* __restrict__ edges_pp,
    const int* __restrict__ edges_ap, float* __restrict__ ws,
    float* __restrict__ out)
{
    // sbuf: [0,3072) 16 tiles x 16 rows x 12 u32; [3072,3328) bias floats
    __shared__ uint32_t sbuf[3328];
    __shared__ float smred[4];
    const int b = blockIdx.x, tid = threadIdx.x, wid = tid >> 6;
    const int lane = tid & 63, quad = lane >> 4, l16 = lane & 15;

    float val = 0.f;
    int slot;

    if (b < NB_MAT) {
        const bool isPP = (b >= NQ_AP);
        int g, c;
        if (!isPP) { g = b >> 5; c = b & 31; }
        else {
            const int qq = b - NQ_AP;
            int m = 0;
            while ((m + 1) * (m + 2) <= qq) ++m;     // band index (uniform SALU)
            const int r = qq - m * (m + 1);
            const int dv = r / (m + 1);
            g = 2 * m + dv; c = r - dv * (m + 1);
        }
        const int t0 = c << 4;
        slot = isPP ? 0 : 2;

        const uint32_t* Xbf = (const uint32_t*)(ws + WS_PSBF);
        const uint32_t* Ybf = (const uint32_t*)(ws + (isPP ? WS_PBF : WS_ABF));
        const float* y2  = ws + (isPP ? WS_Y2P : WS_Y2A);
        const float* gl2 = ws + (isPP ? WS_GL2 : WS_BL2);
        const float* EcA = ws + (isPP ? WS_EGC : WS_EBC);

        // ---- per-wave: two adjacent 16-col strips ----
        const int sA = (g << 3) + (wid << 1);
        bf16x8 bfrag[2];
        float  Ec[2];
#pragma unroll
        for (int ss = 0; ss < 2; ++ss) {
            const int j = ((sA + ss) << 4) + l16;
            u32x4 bu = {0u, 0u, 0u, 0u};
            if (quad < 2)       bu = *(const u32x4*)(Ybf + j * 8 + (quad << 2));
            else if (quad == 2) bu.x = packbf2(1.0f, y2[j]);   // k16=1, k17=y2
            bfrag[ss] = __builtin_bit_cast(bf16x8, bu);
            Ec[ss] = EcA[j];
        }

        // ---- stage chunk: 12 KB A-rows + 1 KB bias, async DMA ----
        for (int k = wid; k < 13; k += 4) {
            const uint32_t* gsrc;
            int loff;
            if (k < 12) { gsrc = Xbf + t0 * 192 + (k << 8); loff = k << 8; }
            else        { gsrc = (const uint32_t*)(gl2 + (t0 << 4)); loff = 3072; }
            gload_lds(gsrc + (lane << 2), &sbuf[loff]);
        }
        __syncthreads();   // drains DMA, staging visible

        const f32x4 zero4 = {0.f, 0.f, 0.f, 0.f};
        const int aq4 = (quad < 2 ? quad : 2) << 2;   // quad3 aliases quad2 (x B=0)
        float acc0 = 0.f, acc1 = 0.f;

        auto full_tile = [&](int t) {
            const int tl = t - t0;
            const u32x4 au = *(const u32x4*)&sbuf[tl * 192 + l16 * 12 + aq4];
            const f32x4 ag4 = *(const f32x4*)((const float*)sbuf + 3072 + (tl << 4) + (quad << 2));
            f32x4 d0 = __builtin_amdgcn_mfma_f32_16x16x32_bf16(
                __builtin_bit_cast(bf16x8, au), bfrag[0], zero4, 0, 0, 0);
            f32x4 d1 = __builtin_amdgcn_mfma_f32_16x16x32_bf16(
                __builtin_bit_cast(bf16x8, au), bfrag[1], zero4, 0, 0, 0);
#pragma unroll
            for (int r = 0; r < 4; ++r) {
                float q0 = fmaxf(d0[r], 0.f), q1 = fmaxf(d1[r], 0.f);
                acc0 += __builtin_amdgcn_exp2f(
                    fmaf(-LOG2E, __builtin_amdgcn_sqrtf(q0), ag4[r]));
                acc1 += __builtin_amdgcn_exp2f(
                    fmaf(-LOG2E, __builtin_amdgcn_sqrtf(q1), ag4[r]));
            }
        };

        const int tFull = isPP ? (sA < t0 + CH ? sA : t0 + CH) : t0 + CH;
        for (int t = t0; t < tFull; ++t) full_tile(t);

        if (isPP && sA < t0 + CH) {       // diagonal pair (last chunk only)
            {   // tile t=sA: ss0 diagonal-masked, ss1 full
                const int tl = sA - t0;
                const u32x4 au = *(const u32x4*)&sbuf[tl * 192 + l16 * 12 + aq4];
                const f32x4 ag4 = *(const f32x4*)((const float*)sbuf + 3072 + (tl << 4) + (quad << 2));
                f32x4 d0 = __builtin_amdgcn_mfma_f32_16x16x32_bf16(
                    __builtin_bit_cast(bf16x8, au), bfrag[0], zero4, 0, 0, 0);
                f32x4 d1 = __builtin_amdgcn_mfma_f32_16x16x32_bf16(
                    __builtin_bit_cast(bf16x8, au), bfrag[1], zero4, 0, 0, 0);
#pragma unroll
                for (int r = 0; r < 4; ++r) {
                    float q0 = fmaxf(d0[r], 0.f), q1 = fmaxf(d1[r], 0.f);
                    float t0v = __builtin_amdgcn_exp2f(
                        fmaf(-LOG2E, __builtin_amdgcn_sqrtf(q0), ag4[r]));
                    if (l16 <= (quad << 2) + r) t0v = 0.f;   // strict j > i
                    acc0 += t0v;
                    acc1 += __builtin_amdgcn_exp2f(
                        fmaf(-LOG2E, __builtin_amdgcn_sqrtf(q1), ag4[r]));
                }
            }
            {   // tile t=sA+1: ss1 diagonal-masked only
                const int tl = sA + 1 - t0;
                const u32x4 au = *(const u32x4*)&sbuf[tl * 192 + l16 * 12 + aq4];
                const f32x4 ag4 = *(const f32x4*)((const float*)sbuf + 3072 + (tl << 4) + (quad << 2));
                f32x4 d1 = __builtin_amdgcn_mfma_f32_16x16x32_bf16(
                    __builtin_bit_cast(bf16x8, au), bfrag[1], zero4, 0, 0, 0);
#pragma unroll
                for (int r = 0; r < 4; ++r) {
                    float q1 = fmaxf(d1[r], 0.f);
                    float t1v = __builtin_amdgcn_exp2f(
                        fmaf(-LOG2E, __builtin_amdgcn_sqrtf(q1), ag4[r]));
                    if (l16 <= (quad << 2) + r) t1v = 0.f;
                    acc1 += t1v;
                }
            }
        }
        val = acc0 * Ec[0] + acc1 * Ec[1];
    } else {
        // ---- edge tail blocks: 128 pp + 128 ap, 2048 edges each ----
        const int  eb   = b - NB_MAT;
        const bool isPP = (eb < 128);
        const int  base = (isPP ? eb : eb - 128) * 2048;
        slot = isPP ? 1 : 3;
        float sum = 0.f;
#pragma unroll
        for (int k = 0; k < 8; ++k) {
            const int e = base + k * 256 + tid;
            const float* yrow;
            float bias;
            int e0;
            if (isPP) {
                e0 = edges_pp[e];
                int e1 = edges_pp[NEDGE + e];
                yrow = p + e1 * DIM;
                bias = gamma_pp[e0] + gamma_pp[N_PP + e1];
            } else {
                e0 = edges_ap[e];
                int e1 = edges_ap[NEDGE + e];
                yrow = a + (e1 - N_PP) * DIM;
                bias = beta_ap[e0] + beta_ap[e1];
            }
            const float4* xp = (const float4*)(p_star + e0 * DIM);
            const float4* yp = (const float4*)yrow;
            float d2 = 0.f;
#pragma unroll
            for (int kk = 0; kk < 4; ++kk) {
                float4 xv = xp[kk], yv = yp[kk];
                float dx = xv.x - yv.x, dy = xv.y - yv.y,
                      dz = xv.z - yv.z, dw = xv.w - yv.w;
                d2 += dx*dx + dy*dy + dz*dz + dw*dw;
            }
            sum += bias - __builtin_amdgcn_sqrtf(d2);
        }
        val = sum;
    }

    float wsum = waveReduce(val);
    if ((tid & 63) == 0) smred[wid] = wsum;
    __syncthreads();
    if (tid == 0) {
        atomicAdd(&ws[slot], smred[0] + smred[1] + smred[2] + smred[3]);
        __threadfence();
        unsigned old = atomicAdd((unsigned*)(ws + 4), 1u);
        if (old == NB_TOTAL - 1) {
            float s0 = atomicAdd(&ws[0], 0.f), s1 = atomicAdd(&ws[1], 0.f);
            float s2 = atomicAdd(&ws[2], 0.f), s3 = atomicAdd(&ws[3], 0.f);
            out[0] = 0.5f * (s0 - s1) / (float)N_PP
                   + 0.5f * (s2 - s3) / (float)N_PP;
        }
    }
}

extern "C" void kernel_launch(void* const* d_in, const int* in_sizes, int n_in,
                              void* d_out, int out_size, void* d_ws, size_t ws_size,
                              hipStream_t stream) {
    const float* p_star   = (const float*)d_in[0];
    const float* p        = (const float*)d_in[1];
    const float* a        = (const float*)d_in[2];
    const float* beta_ap  = (const float*)d_in[3];
    const float* gamma_pp = (const float*)d_in[4];
    const int*   edges_pp = (const int*)d_in[5];
    const int*   edges_ap = (const int*)d_in[6];

    float* ws  = (float*)d_ws;
    float* out = (float*)d_out;

    hipLaunchKernelGGL(pre_kernel, dim3(224), dim3(256), 0, stream,
                       p_star, p, a, beta_ap, gamma_pp, ws);
    hipLaunchKernelGGL(main_kernel, dim3(NB_TOTAL), dim3(256), 0, stream,
                       p_star, p, a, beta_ap, gamma_pp, edges_pp, edges_ap, ws, out);
}